// Round 2
// baseline (1005.913 us; speedup 1.0000x reference)
//
#include <hip/hip_runtime.h>
#include <math.h>

#define NEGF -1000000000.0f
#define EPSF 1e-7f

// B=32, T=256, IN=64, H=128, 4H=512, TOP_K=5

typedef float v4f __attribute__((ext_vector_type(4)));
#define FMA4(a, b, c) __builtin_elementwise_fma((a), (b), (c))

__device__ __forceinline__ float fsigmoid(float x) {
  return 1.0f / (1.0f + __expf(-x));               // overflow -> correct limit
}
__device__ __forceinline__ float ftanh(float x) {
  return 1.0f - 2.0f / (1.0f + __expf(2.0f * x));  // limits +-1: correct
}

// wave64 all-reduce sum via DPP (row_shr 1/2/4/8 + row_bcast 15/31), ~35 cyc.
__device__ __forceinline__ float wave_allsum(float v) {
#if __has_builtin(__builtin_amdgcn_update_dpp) && __has_builtin(__builtin_amdgcn_readlane)
  float f = v;
#define DPPSTEP(ctrl, rmask) { \
    int t = __builtin_amdgcn_update_dpp(0, __builtin_bit_cast(int, f), \
                                        ctrl, rmask, 0xf, true); \
    f += __builtin_bit_cast(float, t); }
  DPPSTEP(0x111, 0xf)   // row_shr:1
  DPPSTEP(0x112, 0xf)   // row_shr:2
  DPPSTEP(0x114, 0xf)   // row_shr:4
  DPPSTEP(0x118, 0xf)   // row_shr:8  -> lane15 of each row has row sum
  DPPSTEP(0x142, 0xa)   // row_bcast:15 into rows 1,3
  DPPSTEP(0x143, 0x8)   // row_bcast:31 into row 3 -> lane 63 = total
#undef DPPSTEP
  return __builtin_bit_cast(float,
      __builtin_amdgcn_readlane(__builtin_bit_cast(int, f), 63));
#else
  for (int off = 1; off < 64; off <<= 1) v += __shfl_xor(v, off, 64);
  return v;
#endif
}

// Single fused kernel: full recurrence, one block per batch element, 1024
// threads. The former xw_kernel (x @ W_ih^T) is folded into Phase A: thread
// (q,p) also holds the W_ih K-chunk for its 2 gates (4 v4f each) and FMAs
// the current x row (staged in a 2-row LDS ring by wave 15 during its idle
// S1->S2 window). All Phase-A dots use ext_vector fma -> v_pk_fma_f32
// (packed fp32, 2x rate): 48 pk-instrs/thread/step vs the old 64 scalar
// FMAs for W_hh alone. This removes the separate kernel launch + the 16 MB
// xw workspace round-trip (~80 us of the round-1 total).
//
// DELTA CANCELLATION (unchanged from round 1):
//   s[t] = a + d[t]; delta = a + top5(d)[4] + EPS  =>  w[t] = d[t]-t5v4-EPS
//   independent of a. Sparse attention = 4 register-indexed LDS row gathers
//   whose addresses are known from the PREVIOUS step (prefetched before S1).
//   Raw-score path (rem<=5) kept as a 5-step special case.
__global__
__attribute__((amdgpu_flat_work_group_size(1024, 1024), amdgpu_waves_per_eu(4, 4)))
void lstm_attn(
    const float* __restrict__ x, const float* __restrict__ W_ih,
    const float* __restrict__ W_hh, const float* __restrict__ b_ih,
    const float* __restrict__ b_hh, const float* __restrict__ w_t,
    float* __restrict__ out)
{
  const int b   = blockIdx.x;
  const int tid = threadIdx.x;
  const int l   = tid & 63;       // lane
  const int wid = tid >> 6;
  const int p   = tid & 255;      // gate-pair id
  const int q   = tid >> 8;       // K-chunk 0..3 (wave-uniform)
  const int gA  = p;
  const int gB  = p + 256;

  __shared__ float ho[257 * 128];     // fp32 h history (131584 B), row i = h after step i-1
  __shared__ float sh_part[4 * 512];  // gate partials [q][gate] (8 KB)
  __shared__ float sx[2][64];         // x-row ring (512 B)
  __shared__ float sh_d[8];           // d[t] cache, only needed for t<5

  // one-time weight load: W_hh chunk (2 gates x 32) + W_ih chunk (2 gates x 16)
  const v4f* pA = (const v4f*)(W_hh + (size_t)gA * 128 + (q << 5));
  const v4f* pB = (const v4f*)(W_hh + (size_t)gB * 128 + (q << 5));
  v4f wA0 = pA[0], wA1 = pA[1], wA2 = pA[2], wA3 = pA[3],
      wA4 = pA[4], wA5 = pA[5], wA6 = pA[6], wA7 = pA[7];
  v4f wB0 = pB[0], wB1 = pB[1], wB2 = pB[2], wB3 = pB[3],
      wB4 = pB[4], wB5 = pB[5], wB6 = pB[6], wB7 = pB[7];
  const v4f* iAp = (const v4f*)(W_ih + (size_t)gA * 64 + (q << 4));
  const v4f* iBp = (const v4f*)(W_ih + (size_t)gB * 64 + (q << 4));
  v4f iA0 = iAp[0], iA1 = iAp[1], iA2 = iAp[2], iA3 = iAp[3];
  v4f iB0 = iBp[0], iB1 = iBp[1], iB2 = iBp[2], iB3 = iBp[3];
  float biasA = 0.0f, biasB = 0.0f;
  if (q == 0) { biasA = b_ih[gA] + b_hh[gA]; biasB = b_ih[gB] + b_hh[gB]; }

  // wave0 per-lane persistent state (h elements j0=2l, j1=2l+1)
  const int j0 = 2 * l, j1 = 2 * l + 1;
  float c0 = 0.0f, c1 = 0.0f;
  float wa0 = 0.0f, wa1 = 0.0f, wb0 = 0.0f, wb1 = 0.0f;
  // running top-5 of d with indices (replicated identically in all wave0 lanes)
  float t5v0 = 0.0f, t5v1 = NEGF, t5v2 = NEGF, t5v3 = NEGF, t5v4 = NEGF;
  int   t5i0 = 0, t5i1 = 0, t5i2 = 0, t5i3 = 0;
  // precomputed (at end of step i-1) normalized gather weights + LDS offsets
  float gn0 = 0.0f, gn1 = 0.0f, gn2 = 0.0f, gn3 = 0.0f;
  int   ofs0 = 0, ofs1 = 0, ofs2 = 0, ofs3 = 0;

  const float* xg = x + (size_t)b * 256 * 64;

  if (wid == 0) {
    wa0 = w_t[j0];       wa1 = w_t[j1];
    wb0 = w_t[128 + j0]; wb1 = w_t[128 + j1];
    *(float2*)(ho + j0) = make_float2(0.0f, 0.0f);   // h(-1) = 0 (row 0)
    __builtin_amdgcn_s_setprio(1);   // wave0 is always the barrier straggler
  }
  if (wid == 15) sx[0][l] = xg[l];   // stage x row 0
  if (tid == 0) sh_d[0] = 0.0f;
  __syncthreads();

  for (int i = 0; i < 256; ++i) {
    const int rem = i + 1;
    float hn0 = 0.0f, hn1 = 0.0f;

    // wave15: issue next x-row load early (consumed after S1, hidden latency)
    float xnext = 0.0f;
    if (wid == 15 && i < 255) xnext = xg[(size_t)(i + 1) * 64 + l];

    // ---- Phase A: gate partials, packed-fp32 FMAs ----
    const v4f* xr = (const v4f*)(&sx[i & 1][q << 4]);
    v4f xv0 = xr[0], xv1 = xr[1], xv2 = xr[2], xv3 = xr[3];
    v4f accA = {biasA, 0.0f, 0.0f, 0.0f};
    v4f accB = {biasB, 0.0f, 0.0f, 0.0f};
    accA = FMA4(iA0, xv0, accA); accA = FMA4(iA1, xv1, accA);
    accA = FMA4(iA2, xv2, accA); accA = FMA4(iA3, xv3, accA);
    accB = FMA4(iB0, xv0, accB); accB = FMA4(iB1, xv1, accB);
    accB = FMA4(iB2, xv2, accB); accB = FMA4(iB3, xv3, accB);
    const v4f* hh4 = (const v4f*)(ho + i * 128 + (q << 5));
#define LSTEP(j) { v4f hv = hh4[j]; \
    accA = FMA4(wA##j, hv, accA); accB = FMA4(wB##j, hv, accB); }
    LSTEP(0) LSTEP(1) LSTEP(2) LSTEP(3) LSTEP(4) LSTEP(5) LSTEP(6) LSTEP(7)
#undef LSTEP
    sh_part[(q << 9) + gA] = (accA.x + accA.y) + (accA.z + accA.w);
    sh_part[(q << 9) + gB] = (accB.x + accB.y) + (accB.z + accB.w);

    // gather prefetch: addresses known from previous step's top-5; ho rows
    // are append-only so reading before the barrier is race-free.
    float2 hv0, hv1, hv2, hv3;
    if (wid == 0 && i >= 5) {
      hv0 = *(const float2*)(ho + ofs0);
      hv1 = *(const float2*)(ho + ofs1);
      hv2 = *(const float2*)(ho + ofs2);
      hv3 = *(const float2*)(ho + ofs3);
    }
    __syncthreads();                                      // S1

    if (wid == 0) {
      // ---- Phase B: LSTM cell (2 elements/lane) ----
#define GSUM(base) ({ \
      float2 x0 = ((const float2*)(sh_part        + (base)))[l]; \
      float2 x1 = ((const float2*)(sh_part +  512 + (base)))[l]; \
      float2 x2 = ((const float2*)(sh_part + 1024 + (base)))[l]; \
      float2 x3 = ((const float2*)(sh_part + 1536 + (base)))[l]; \
      float2 r; r.x = (x0.x + x1.x) + (x2.x + x3.x); \
      r.y = (x0.y + x1.y) + (x2.y + x3.y); r; })
      float2 Pi = GSUM(0), Pf = GSUM(128), Pg = GSUM(256), Po = GSUM(384);
#undef GSUM
      c0 = fsigmoid(Pf.x) * c0 + fsigmoid(Pi.x) * ftanh(Pg.x);
      c1 = fsigmoid(Pf.y) * c1 + fsigmoid(Pi.y) * ftanh(Pg.y);
      float hc0 = fsigmoid(Po.x) * ftanh(c0);
      float hc1 = fsigmoid(Po.y) * ftanh(c1);

      float at0, at1;
      if (i >= 5) {
        // ---- sparse attention: 4 pre-fetched rows, register weights ----
        at0 = gn0 * hv0.x;            at1 = gn0 * hv0.y;
        at0 = fmaf(gn1, hv1.x, at0);  at1 = fmaf(gn1, hv1.y, at1);
        at0 = fmaf(gn2, hv2.x, at0);  at1 = fmaf(gn2, hv2.y, at1);
        at0 = fmaf(gn3, hv3.x, at0);  at1 = fmaf(gn3, hv3.y, at1);
      } else {
        // ---- rem<=5: attn weights are RAW scores s = a + d[t], no norm ----
        float a = wave_allsum(ftanh(hc0) * wa0 + ftanh(hc1) * wa1);
        at0 = 0.0f; at1 = 0.0f;
        for (int t = 0; t <= i; ++t) {
          float s = a + sh_d[t];
          float2 hv = *(const float2*)(ho + t * 128 + j0);
          at0 = fmaf(s, hv.x, at0);
          at1 = fmaf(s, hv.y, at1);
        }
      }
      hn0 = hc0 + at0; hn1 = hc1 + at1;
      *(float2*)(ho + rem * 128 + j0) = make_float2(hn0, hn1);
      if (i == 255) {
        out[b * 128 + j0] = at0; out[b * 128 + j1] = at1;   // attn_c
        // attn_w: zero except at the <=4 above-threshold top-5 indices
        #pragma unroll
        for (int m = 0; m < 4; ++m) {
          int t = l + 64 * m;
          float val = 0.0f;
          if (t == t5i0) val = gn0;
          if (t == t5i1) val = gn1;
          if (t == t5i2) val = gn2;
          if (t == t5i3) val = gn3;
          out[4096 + b * 256 + t] = val;
        }
      }
    } else if (wid == 15 && i < 255) {
      sx[(i + 1) & 1][l] = xnext;     // idle window: publish next x row
    }
    __syncthreads();                                      // S2

    // ---- tail (off critical path: overlaps other waves' next Phase A) ----
    if (wid == 0 && i < 255) {
      float dn = wave_allsum(ftanh(hn0) * wb0 + ftanh(hn1) * wb1);
      if (l == 0 && i < 4) sh_d[rem] = dn;   // only raw-score steps read it
      // replicated top-5 (value,index) insert — identical in every lane
      float v = dn; int vi = rem;
      if (v > t5v0) { float tv = t5v0; int ti = t5i0; t5v0 = v; t5i0 = vi; v = tv; vi = ti; }
      if (v > t5v1) { float tv = t5v1; int ti = t5i1; t5v1 = v; t5i1 = vi; v = tv; vi = ti; }
      if (v > t5v2) { float tv = t5v2; int ti = t5i2; t5v2 = v; t5i2 = vi; v = tv; vi = ti; }
      if (v > t5v3) { float tv = t5v3; int ti = t5i3; t5v3 = v; t5i3 = vi; v = tv; vi = ti; }
      if (v > t5v4) { t5v4 = v; }
      // next step's normalized gather weights + offsets (delta cancellation:
      // w[t] = d[t] - t5v4 - EPS, nonzero only among top-4)
      float g0 = fmaxf(t5v0 - t5v4 - EPSF, 0.0f);
      float g1 = fmaxf(t5v1 - t5v4 - EPSF, 0.0f);
      float g2 = fmaxf(t5v2 - t5v4 - EPSF, 0.0f);
      float g3 = fmaxf(t5v3 - t5v4 - EPSF, 0.0f);
      float inv = 1.0f / (((g0 + g1) + (g2 + g3)) + EPSF);
      gn0 = g0 * inv; gn1 = g1 * inv; gn2 = g2 * inv; gn3 = g3 * inv;
      ofs0 = (t5i0 << 7) + j0; ofs1 = (t5i1 << 7) + j0;
      ofs2 = (t5i2 << 7) + j0; ofs3 = (t5i3 << 7) + j0;
    }
  }
}

extern "C" void kernel_launch(void* const* d_in, const int* in_sizes, int n_in,
                              void* d_out, int out_size, void* d_ws, size_t ws_size,
                              hipStream_t stream) {
  const float* x    = (const float*)d_in[0];  // (32,256,64)
  const float* W_ih = (const float*)d_in[1];  // (512,64)
  const float* W_hh = (const float*)d_in[2];  // (512,128)
  const float* b_ih = (const float*)d_in[3];  // (512,)
  const float* b_hh = (const float*)d_in[4];  // (512,)
  const float* w_t  = (const float*)d_in[5];  // (256,1)
  float* out = (float*)d_out;                 // [0:4096) attn_c, [4096:12288) attn_w

  (void)d_ws; (void)ws_size;                  // workspace no longer needed
  lstm_attn<<<dim3(32), 1024, 0, stream>>>(x, W_ih, W_hh, b_ih, b_hh, w_t, out);
}

// Round 3
// 412.747 us; speedup vs baseline: 2.4371x; 2.4371x over previous
//
#include <hip/hip_runtime.h>
#include <math.h>

#define NEGF -1000000000.0f
#define EPSF 1e-7f

// B=32, T=256, IN=64, H=128, 4H=512, TOP_K=5

__device__ __forceinline__ float fsigmoid(float x) {
  return 1.0f / (1.0f + __expf(-x));               // overflow -> correct limit
}
__device__ __forceinline__ float ftanh(float x) {
  return 1.0f - 2.0f / (1.0f + __expf(2.0f * x));  // limits +-1: correct
}

// wave64 all-reduce sum via DPP (row_shr 1/2/4/8 + row_bcast 15/31), ~35 cyc.
__device__ __forceinline__ float wave_allsum(float v) {
#if __has_builtin(__builtin_amdgcn_update_dpp) && __has_builtin(__builtin_amdgcn_readlane)
  float f = v;
#define DPPSTEP(ctrl, rmask) { \
    int t = __builtin_amdgcn_update_dpp(0, __builtin_bit_cast(int, f), \
                                        ctrl, rmask, 0xf, true); \
    f += __builtin_bit_cast(float, t); }
  DPPSTEP(0x111, 0xf)   // row_shr:1
  DPPSTEP(0x112, 0xf)   // row_shr:2
  DPPSTEP(0x114, 0xf)   // row_shr:4
  DPPSTEP(0x118, 0xf)   // row_shr:8  -> lane15 of each row has row sum
  DPPSTEP(0x142, 0xa)   // row_bcast:15 into rows 1,3
  DPPSTEP(0x143, 0x8)   // row_bcast:31 into row 3 -> lane 63 = total
#undef DPPSTEP
  return __builtin_bit_cast(float,
      __builtin_amdgcn_readlane(__builtin_bit_cast(int, f), 63));
#else
  for (int off = 1; off < 64; off <<= 1) v += __shfl_xor(v, off, 64);
  return v;
#endif
}

// Kernel 1: xw[b][t][g] = x[b][t] . W_ih[g] + (b_ih[g]+b_hh[g])
// grid (8, 32) = 256 blocks (1/CU), 512 threads. Thread owns ONE gate row
// (16 float4 = 64 VGPR) loaded ONCE and amortized over a 32-token tile
// (rounds 0/1 re-loaded W per 8 tokens from 2048 tiny blocks -> the W row
// loads, 256B-strided across lanes, fragmented into 64 txns/instr and
// dominated at ~70 us). x tile staged coalesced in LDS (512 float4 = 1/thread),
// read back as wave-uniform broadcasts; stores coalesced (512 floats/row).
__global__ __launch_bounds__(512) void xw_kernel(
    const float* __restrict__ x, const float* __restrict__ W_ih,
    const float* __restrict__ b_ih, const float* __restrict__ b_hh,
    float* __restrict__ xw)
{
  const int t0 = blockIdx.x * 32;
  const int b  = blockIdx.y;
  const int g  = threadIdx.x;

  __shared__ float sx[32 * 64];              // 8 KB
  ((float4*)sx)[threadIdx.x] =
      ((const float4*)(x + (size_t)(b * 256 + t0) * 64))[threadIdx.x];

  const float4* wr = (const float4*)(W_ih + (size_t)g * 64);
  float4 w0 = wr[0],  w1 = wr[1],  w2 = wr[2],  w3 = wr[3],
         w4 = wr[4],  w5 = wr[5],  w6 = wr[6],  w7 = wr[7],
         w8 = wr[8],  w9 = wr[9],  w10 = wr[10], w11 = wr[11],
         w12 = wr[12], w13 = wr[13], w14 = wr[14], w15 = wr[15];
  const float bias = b_ih[g] + b_hh[g];
  __syncthreads();

  float* dst = xw + (size_t)(b * 256 + t0) * 512 + g;
  for (int tt = 0; tt < 32; ++tt) {
    const float4* xr = (const float4*)(sx + tt * 64);
    float a0 = 0.0f, a1 = 0.0f, a2 = 0.0f, a3 = 0.0f;
#define XSTEP(j) { float4 hv = xr[j]; \
    a0 = fmaf(w##j.x, hv.x, a0); a1 = fmaf(w##j.y, hv.y, a1); \
    a2 = fmaf(w##j.z, hv.z, a2); a3 = fmaf(w##j.w, hv.w, a3); }
    XSTEP(0) XSTEP(1) XSTEP(2) XSTEP(3) XSTEP(4) XSTEP(5) XSTEP(6) XSTEP(7)
    XSTEP(8) XSTEP(9) XSTEP(10) XSTEP(11) XSTEP(12) XSTEP(13) XSTEP(14) XSTEP(15)
#undef XSTEP
    dst[(size_t)tt * 512] = (a0 + a1) + (a2 + a3) + bias;
  }
}

// Kernel 2: full recurrence, one block per batch element, 1024 threads.
// EXACT round-1 structure (measured 333.7 us; round-2's fused W_ih registers
// overflowed the 128-VGPR cap -> scratch spill -> 993 us. Reverted.)
//
// DELTA CANCELLATION:
//   s[t] = a + d[t]; delta = a + top5(d)[4] + EPS  =>  w[t] = d[t]-t5v4-EPS
//   independent of a. Sparse attention = 4 register-indexed LDS row gathers
//   whose addresses are known from the PREVIOUS step (prefetched before S1).
//   Raw-score path (rem<=5) kept as a 5-step special case.
__global__
__attribute__((amdgpu_flat_work_group_size(1024, 1024), amdgpu_waves_per_eu(4, 4)))
void lstm_attn(
    const float* __restrict__ xw, const float* __restrict__ W_hh,
    const float* __restrict__ w_t, float* __restrict__ out)
{
  const int b   = blockIdx.x;
  const int tid = threadIdx.x;
  const int l   = tid & 63;       // lane
  const int wid = tid >> 6;
  const int p   = tid & 255;      // gate-pair id
  const int q   = tid >> 8;       // K-chunk 0..3 (wave-uniform)
  const int gA  = p;
  const int gB  = p + 256;

  __shared__ float ho[257 * 128];     // fp32 h history (131584 B), row i = h after step i-1
  __shared__ float sh_part[4 * 512];  // gate partials [q][gate] (8 KB)
  __shared__ float sh_d[8];           // d[t] cache, only needed for t<5

  // one-time weight load: 16 named float4 = 64 regs
  const float4* pA = (const float4*)(W_hh + (size_t)gA * 128 + (q << 5));
  const float4* pB = (const float4*)(W_hh + (size_t)gB * 128 + (q << 5));
  float4 wA0 = pA[0], wA1 = pA[1], wA2 = pA[2], wA3 = pA[3],
         wA4 = pA[4], wA5 = pA[5], wA6 = pA[6], wA7 = pA[7];
  float4 wB0 = pB[0], wB1 = pB[1], wB2 = pB[2], wB3 = pB[3],
         wB4 = pB[4], wB5 = pB[5], wB6 = pB[6], wB7 = pB[7];

  // wave0 per-lane persistent state (h elements j0=2l, j1=2l+1)
  const int j0 = 2 * l, j1 = 2 * l + 1;
  float c0 = 0.0f, c1 = 0.0f;
  float wa0 = 0.0f, wa1 = 0.0f, wb0 = 0.0f, wb1 = 0.0f;
  // running top-5 of d with indices (replicated identically in all wave0 lanes)
  float t5v0 = 0.0f, t5v1 = NEGF, t5v2 = NEGF, t5v3 = NEGF, t5v4 = NEGF;
  int   t5i0 = 0, t5i1 = 0, t5i2 = 0, t5i3 = 0;
  // precomputed (at end of step i-1) normalized gather weights + LDS offsets
  float gn0 = 0.0f, gn1 = 0.0f, gn2 = 0.0f, gn3 = 0.0f;
  int   ofs0 = 0, ofs1 = 0, ofs2 = 0, ofs3 = 0;

  if (wid == 0) {
    wa0 = w_t[j0];       wa1 = w_t[j1];
    wb0 = w_t[128 + j0]; wb1 = w_t[128 + j1];
    *(float2*)(ho + j0) = make_float2(0.0f, 0.0f);   // h(-1) = 0 (row 0)
    __builtin_amdgcn_s_setprio(1);   // wave0 is always the barrier straggler
  }
  if (tid == 0) sh_d[0] = 0.0f;
  __syncthreads();

  const float* xwb = xw + (size_t)b * 256 * 512;
  float xcurA = 0.0f, xcurB = 0.0f;
  if (q == 0) { xcurA = xwb[gA]; xcurB = xwb[gB]; }

  for (int i = 0; i < 256; ++i) {
    const int rem = i + 1;
    float hn0 = 0.0f, hn1 = 0.0f;

    // ---- Phase A: gate partials (64 FMAs from resident fp32 weights) ----
    float aA0 = xcurA, aA1 = 0.0f, aB0 = xcurB, aB1 = 0.0f;
    if (q == 0 && i < 255) {          // prefetch next step's xw
      xcurA = xwb[(size_t)(i + 1) * 512 + gA];
      xcurB = xwb[(size_t)(i + 1) * 512 + gB];
    }
    const float4* hh4 = (const float4*)(ho + i * 128 + (q << 5));
#define LSTEP(j) { float4 hv = hh4[j]; \
    aA0 = fmaf(wA##j.x, hv.x, aA0); aA1 = fmaf(wA##j.y, hv.y, aA1); \
    aA0 = fmaf(wA##j.z, hv.z, aA0); aA1 = fmaf(wA##j.w, hv.w, aA1); \
    aB0 = fmaf(wB##j.x, hv.x, aB0); aB1 = fmaf(wB##j.y, hv.y, aB1); \
    aB0 = fmaf(wB##j.z, hv.z, aB0); aB1 = fmaf(wB##j.w, hv.w, aB1); }
    LSTEP(0) LSTEP(1) LSTEP(2) LSTEP(3) LSTEP(4) LSTEP(5) LSTEP(6) LSTEP(7)
#undef LSTEP
    sh_part[(q << 9) + gA] = aA0 + aA1;
    sh_part[(q << 9) + gB] = aB0 + aB1;

    // gather prefetch: addresses known from previous step's top-5; ho rows
    // are append-only so reading before the barrier is race-free.
    float2 hv0, hv1, hv2, hv3;
    if (wid == 0 && i >= 5) {
      hv0 = *(const float2*)(ho + ofs0);
      hv1 = *(const float2*)(ho + ofs1);
      hv2 = *(const float2*)(ho + ofs2);
      hv3 = *(const float2*)(ho + ofs3);
    }
    __syncthreads();                                      // S1

    if (wid == 0) {
      // ---- Phase B: LSTM cell (2 elements/lane) ----
#define GSUM(base) ({ \
      float2 x0 = ((const float2*)(sh_part        + (base)))[l]; \
      float2 x1 = ((const float2*)(sh_part +  512 + (base)))[l]; \
      float2 x2 = ((const float2*)(sh_part + 1024 + (base)))[l]; \
      float2 x3 = ((const float2*)(sh_part + 1536 + (base)))[l]; \
      float2 r; r.x = (x0.x + x1.x) + (x2.x + x3.x); \
      r.y = (x0.y + x1.y) + (x2.y + x3.y); r; })
      float2 Pi = GSUM(0), Pf = GSUM(128), Pg = GSUM(256), Po = GSUM(384);
#undef GSUM
      c0 = fsigmoid(Pf.x) * c0 + fsigmoid(Pi.x) * ftanh(Pg.x);
      c1 = fsigmoid(Pf.y) * c1 + fsigmoid(Pi.y) * ftanh(Pg.y);
      float hc0 = fsigmoid(Po.x) * ftanh(c0);
      float hc1 = fsigmoid(Po.y) * ftanh(c1);

      float at0, at1;
      if (i >= 5) {
        // ---- sparse attention: 4 pre-fetched rows, register weights ----
        at0 = gn0 * hv0.x;            at1 = gn0 * hv0.y;
        at0 = fmaf(gn1, hv1.x, at0);  at1 = fmaf(gn1, hv1.y, at1);
        at0 = fmaf(gn2, hv2.x, at0);  at1 = fmaf(gn2, hv2.y, at1);
        at0 = fmaf(gn3, hv3.x, at0);  at1 = fmaf(gn3, hv3.y, at1);
      } else {
        // ---- rem<=5: attn weights are RAW scores s = a + d[t], no norm ----
        float a = wave_allsum(ftanh(hc0) * wa0 + ftanh(hc1) * wa1);
        at0 = 0.0f; at1 = 0.0f;
        for (int t = 0; t <= i; ++t) {
          float s = a + sh_d[t];
          float2 hv = *(const float2*)(ho + t * 128 + j0);
          at0 = fmaf(s, hv.x, at0);
          at1 = fmaf(s, hv.y, at1);
        }
      }
      hn0 = hc0 + at0; hn1 = hc1 + at1;
      *(float2*)(ho + rem * 128 + j0) = make_float2(hn0, hn1);
      if (i == 255) {
        out[b * 128 + j0] = at0; out[b * 128 + j1] = at1;   // attn_c
        // attn_w: zero except at the <=4 above-threshold top-5 indices
        #pragma unroll
        for (int m = 0; m < 4; ++m) {
          int t = l + 64 * m;
          float val = 0.0f;
          if (t == t5i0) val = gn0;
          if (t == t5i1) val = gn1;
          if (t == t5i2) val = gn2;
          if (t == t5i3) val = gn3;
          out[4096 + b * 256 + t] = val;
        }
      }
    }
    __syncthreads();                                      // S2

    // ---- tail (off critical path: overlaps other waves' next Phase A) ----
    if (wid == 0 && i < 255) {
      float dn = wave_allsum(ftanh(hn0) * wb0 + ftanh(hn1) * wb1);
      if (l == 0 && i < 4) sh_d[rem] = dn;   // only raw-score steps read it
      // replicated top-5 (value,index) insert — identical in every lane
      float v = dn; int vi = rem;
      if (v > t5v0) { float tv = t5v0; int ti = t5i0; t5v0 = v; t5i0 = vi; v = tv; vi = ti; }
      if (v > t5v1) { float tv = t5v1; int ti = t5i1; t5v1 = v; t5i1 = vi; v = tv; vi = ti; }
      if (v > t5v2) { float tv = t5v2; int ti = t5i2; t5v2 = v; t5i2 = vi; v = tv; vi = ti; }
      if (v > t5v3) { float tv = t5v3; int ti = t5i3; t5v3 = v; t5i3 = vi; v = tv; vi = ti; }
      if (v > t5v4) { t5v4 = v; }
      // next step's normalized gather weights + offsets (delta cancellation:
      // w[t] = d[t] - t5v4 - EPS, nonzero only among top-4)
      float g0 = fmaxf(t5v0 - t5v4 - EPSF, 0.0f);
      float g1 = fmaxf(t5v1 - t5v4 - EPSF, 0.0f);
      float g2 = fmaxf(t5v2 - t5v4 - EPSF, 0.0f);
      float g3 = fmaxf(t5v3 - t5v4 - EPSF, 0.0f);
      float inv = 1.0f / (((g0 + g1) + (g2 + g3)) + EPSF);
      gn0 = g0 * inv; gn1 = g1 * inv; gn2 = g2 * inv; gn3 = g3 * inv;
      ofs0 = (t5i0 << 7) + j0; ofs1 = (t5i1 << 7) + j0;
      ofs2 = (t5i2 << 7) + j0; ofs3 = (t5i3 << 7) + j0;
    }
  }
}

extern "C" void kernel_launch(void* const* d_in, const int* in_sizes, int n_in,
                              void* d_out, int out_size, void* d_ws, size_t ws_size,
                              hipStream_t stream) {
  const float* x    = (const float*)d_in[0];  // (32,256,64)
  const float* W_ih = (const float*)d_in[1];  // (512,64)
  const float* W_hh = (const float*)d_in[2];  // (512,128)
  const float* b_ih = (const float*)d_in[3];  // (512,)
  const float* b_hh = (const float*)d_in[4];  // (512,)
  const float* w_t  = (const float*)d_in[5];  // (256,1)
  float* out = (float*)d_out;                 // [0:4096) attn_c, [4096:12288) attn_w

  float* xw = (float*)d_ws;                   // 32*256*512 fp32 = 16 MB

  xw_kernel<<<dim3(8, 32), 512, 0, stream>>>(x, W_ih, b_ih, b_hh, xw);
  lstm_attn<<<dim3(32), 1024, 0, stream>>>(xw, W_hh, w_t, out);
}